// Round 4
// baseline (135.937 us; speedup 1.0000x reference)
//
#include <hip/hip_runtime.h>
#include <hip/hip_bf16.h>

#define R_ 256
#define B_ 64
#define D_ 512
#define N_ 16
#define K_ 4
#define RBD (B_ * D_)          // 32768 floats per region
#define OUT_ELEMS (R_ * B_ * D_)
#define M_TOT (R_ * B_)        // 16384
#define GSLICES 64             // gram split-K slices (K-chunk 512)

typedef __attribute__((address_space(1))) unsigned int g_u32;
typedef __attribute__((address_space(3))) unsigned int l_u32;
using f32x4 = __attribute__((ext_vector_type(4))) float;
using f16x8 = __attribute__((ext_vector_type(8))) _Float16;
using f16x4 = __attribute__((ext_vector_type(4))) _Float16;

// ---------------------------------------------------------------------------
// Kernel 1 (prep): fused independent pre-work.
//  - blocks [0, 8192):    h -> A16 = fp16(h), Alo16 = fp16(h - A16)   (flat)
//  - blocks [8192, 8448): W2eff = Wm2 @ Wmsg -> fp16 W16[e][512+d]
//  - blocks [8448, 8704): W16[e][d] = fp16(Wm[e][d]), d < 512
//  - blocks [8704, 8706): bias_eff[e] = b_merge[e] + b_msg . Wm2[e]
// ---------------------------------------------------------------------------
#define PREP_CONV 8192
#define PREP_W2EFF (PREP_CONV + 256)
#define PREP_WCONV (PREP_W2EFF + 256)
#define PREP_TOTAL (PREP_WCONV + 2)

__global__ __launch_bounds__(256) void prep_kernel(
    const float* __restrict__ h, const float* __restrict__ Wmsg,
    const float* __restrict__ b_msg, const float* __restrict__ Wm,
    const float* __restrict__ b_merge, _Float16* __restrict__ A16,
    _Float16* __restrict__ Alo16, _Float16* __restrict__ W16,
    float* __restrict__ bias_eff) {
  const int bx = blockIdx.x;
  const int t = threadIdx.x;
  __shared__ float As[32][33];
  __shared__ float Bs[32][33];

  if (bx < PREP_CONV) {
    const int i = bx * 256 + t;  // float4 id, 0..2097151
    float4 v = *(const float4*)&h[(size_t)i * 4];
    _Float16 hx = (_Float16)v.x, hy = (_Float16)v.y;
    _Float16 hz = (_Float16)v.z, hw = (_Float16)v.w;
    f16x4 hi = {hx, hy, hz, hw};
    f16x4 lo = {(_Float16)(v.x - (float)hx), (_Float16)(v.y - (float)hy),
                (_Float16)(v.z - (float)hz), (_Float16)(v.w - (float)hw)};
    *(f16x4*)&A16[(size_t)i * 4] = hi;
    *(f16x4*)&Alo16[(size_t)i * 4] = lo;
  } else if (bx < PREP_W2EFF) {
    const int bxx = bx - PREP_CONV;
    const int eb = (bxx >> 4) * 32;
    const int db = (bxx & 15) * 32;
    const int tx = t % 16, ty = t / 16;
    const int lr = t / 8;
    const int lc = (t % 8) * 4;
    float a00 = 0.f, a01 = 0.f, a10 = 0.f, a11 = 0.f;
    for (int c0 = 0; c0 < 512; c0 += 32) {
      float4 av = *(const float4*)&Wm[(size_t)(eb + lr) * 1024 + 512 + c0 + lc];
      float4 bv = *(const float4*)&Wmsg[(size_t)(c0 + lr) * 512 + db + lc];
      As[lr][lc + 0] = av.x; As[lr][lc + 1] = av.y;
      As[lr][lc + 2] = av.z; As[lr][lc + 3] = av.w;
      Bs[lr][lc + 0] = bv.x; Bs[lr][lc + 1] = bv.y;
      Bs[lr][lc + 2] = bv.z; Bs[lr][lc + 3] = bv.w;
      __syncthreads();
#pragma unroll
      for (int kk = 0; kk < 32; kk++) {
        float x0 = As[2 * ty + 0][kk], x1 = As[2 * ty + 1][kk];
        float y0 = Bs[kk][2 * tx + 0], y1 = Bs[kk][2 * tx + 1];
        a00 += x0 * y0; a01 += x0 * y1;
        a10 += x1 * y0; a11 += x1 * y1;
      }
      __syncthreads();
    }
    W16[(size_t)(eb + 2 * ty + 0) * 1024 + 512 + db + 2 * tx + 0] = (_Float16)a00;
    W16[(size_t)(eb + 2 * ty + 0) * 1024 + 512 + db + 2 * tx + 1] = (_Float16)a01;
    W16[(size_t)(eb + 2 * ty + 1) * 1024 + 512 + db + 2 * tx + 0] = (_Float16)a10;
    W16[(size_t)(eb + 2 * ty + 1) * 1024 + 512 + db + 2 * tx + 1] = (_Float16)a11;
  } else if (bx < PREP_WCONV) {
    const int i = (bx - PREP_W2EFF) * 256 + t;  // 0..65535 float4 ids
    const int e = i >> 7;
    const int c4 = (i & 127) * 4;
    float4 v = *(const float4*)&Wm[(size_t)e * 1024 + c4];
    f16x4 o = {(_Float16)v.x, (_Float16)v.y, (_Float16)v.z, (_Float16)v.w};
    *(f16x4*)&W16[(size_t)e * 1024 + c4] = o;
  } else {
    const int e = (bx - PREP_WCONV) * 256 + t;  // 0..511
    const float4* bp = (const float4*)b_msg;
    const float4* wp = (const float4*)&Wm[(size_t)e * 1024 + 512];
    float acc = 0.f;
    for (int c = 0; c < 128; c++) {
      float4 b4 = bp[c], w4 = wp[c];
      acc += b4.x * w4.x + b4.y * w4.y + b4.z * w4.z + b4.w * w4.w;
    }
    bias_eff[e] = acc + b_merge[e];
  }
}

// ---------------------------------------------------------------------------
// Kernel 2 (gram): split-precision Gram partials via fp16 MFMA.
//   C1p[s] += Hi_I . Hi_J^T ; C2p[s] += Hi_I . Lo_J^T   over K-chunk s.
// Hi[r] = A16 + r*32768 elems (contiguous 64 KB run). Grid (2,2,GSLICES).
// 128x128 tile, BK=64, 4 waves 2x2, XOR-swizzled LDS via pre-swizzled src.
// ---------------------------------------------------------------------------
__global__ __launch_bounds__(256) void gram_kernel(
    const _Float16* __restrict__ Hi, const _Float16* __restrict__ Lo,
    float* __restrict__ C1p, float* __restrict__ C2p) {
  const int t = threadIdx.x;
  const int lane = t & 63;
  const int w = t >> 6;
  const int I = blockIdx.x * 128;
  const int J = blockIdx.y * 128;
  const int s = blockIdx.z;
  __shared__ char sHiI[128 * 128];  // 128 rows x 128 B (64 fp16), swizzled
  __shared__ char sHiJ[128 * 128];
  __shared__ char sLoJ[128 * 128];
  const int wm = w >> 1, wn = w & 1;
  const int rlane = lane & 15;
  const int kq = lane >> 4;
  const int row_in_sweep = t >> 3;
  const int slot_st = t & 7;

  f32x4 c1[4][4] = {};
  f32x4 c2[4][4] = {};

  const char* HiB = (const char*)Hi;
  const char* LoB = (const char*)Lo;
  const size_t kbase = (size_t)s * 1024;  // bytes: s * 512 elems * 2B

  for (int it = 0; it < 8; ++it) {
#pragma unroll
    for (int q = 0; q < 4; ++q) {
      const int row = q * 32 + row_in_sweep;
      const int slot = slot_st ^ (row & 7);
      const size_t koff = kbase + it * 128 + slot * 16;
      const char* gi = HiB + (size_t)(I + row) * 65536 + koff;
      const char* gj = HiB + (size_t)(J + row) * 65536 + koff;
      const char* gl = LoB + (size_t)(J + row) * 65536 + koff;
      char* di = sHiI + q * 4096 + w * 1024;  // linear dest; HW adds lane*16
      char* dj = sHiJ + q * 4096 + w * 1024;
      char* dl = sLoJ + q * 4096 + w * 1024;
      __builtin_amdgcn_global_load_lds((const g_u32*)gi, (l_u32*)di, 16, 0, 0);
      __builtin_amdgcn_global_load_lds((const g_u32*)gj, (l_u32*)dj, 16, 0, 0);
      __builtin_amdgcn_global_load_lds((const g_u32*)gl, (l_u32*)dl, 16, 0, 0);
    }
    __syncthreads();
#pragma unroll
    for (int ks = 0; ks < 2; ++ks) {
      f16x8 ai[4], bj[4], lj[4];
#pragma unroll
      for (int i = 0; i < 4; ++i) {
        const int row = wm * 64 + i * 16 + rlane;
        const int slot = (ks * 4 + kq) ^ (row & 7);
        ai[i] = *(const f16x8*)(sHiI + row * 128 + slot * 16);
      }
#pragma unroll
      for (int j = 0; j < 4; ++j) {
        const int row = wn * 64 + j * 16 + rlane;
        const int slot = (ks * 4 + kq) ^ (row & 7);
        bj[j] = *(const f16x8*)(sHiJ + row * 128 + slot * 16);
        lj[j] = *(const f16x8*)(sLoJ + row * 128 + slot * 16);
      }
#pragma unroll
      for (int i = 0; i < 4; ++i)
#pragma unroll
        for (int j = 0; j < 4; ++j) {
          c1[i][j] = __builtin_amdgcn_mfma_f32_16x16x32_f16(ai[i], bj[j],
                                                            c1[i][j], 0, 0, 0);
          c2[i][j] = __builtin_amdgcn_mfma_f32_16x16x32_f16(ai[i], lj[j],
                                                            c2[i][j], 0, 0, 0);
        }
    }
    __syncthreads();
  }

#pragma unroll
  for (int i = 0; i < 4; ++i) {
#pragma unroll
    for (int reg = 0; reg < 4; ++reg) {
      const int gr = I + wm * 64 + i * 16 + kq * 4 + reg;
      const size_t base = ((size_t)s * 256 + gr) * 256 + J + wn * 64 + rlane;
      float* p1 = C1p + base;
      float* p2 = C2p + base;
#pragma unroll
      for (int j = 0; j < 4; ++j) {
        p1[j * 16] = c1[i][j][reg];
        p2[j * 16] = c2[i][j][reg];
      }
    }
  }
}

// ---------------------------------------------------------------------------
// Kernel 3: reduce partials in fixed order -> sims; stable top-4 (strict >,
// first index wins = jax.lax.top_k tie rule). 1 wave per region.
// G[r][j] = sum_s C1p[s][r][j] + C2p[s][r][j] + C2p[s][j][r]
// ---------------------------------------------------------------------------
__global__ __launch_bounds__(64) void reduce_topk_kernel(
    const float* __restrict__ C1p, const float* __restrict__ C2p,
    const int* __restrict__ nbrs, int* __restrict__ sel,
    float* __restrict__ fanin) {
  const int r = blockIdx.x;
  const int t = threadIdx.x;
  const int n = t >> 2;       // 0..15
  const int sq = t & 3;       // 0..3
  __shared__ float sims_s[N_];
  __shared__ int nb_s[N_];
  if (t < N_) nb_s[t] = nbrs[r * N_ + t];
  __syncthreads();
  const int j = nbrs[r * N_ + n];
  float acc = 0.f;
  // slices sq*16 .. sq*16+15, fixed order within and across lanes
  for (int s = sq * 16; s < sq * 16 + 16; ++s) {
    const size_t rj = ((size_t)s * 256 + r) * 256 + j;
    const size_t jr = ((size_t)s * 256 + j) * 256 + r;
    acc += C1p[rj] + C2p[rj] + C2p[jr];
  }
  acc += __shfl_xor(acc, 1);
  acc += __shfl_xor(acc, 2);
  if (sq == 0) sims_s[n] = acc;
  __syncthreads();
  if (t == 0) {
    unsigned used = 0;
#pragma unroll
    for (int k = 0; k < K_; k++) {
      float best = -3.0e38f;
      int bi = 0;
      for (int nn = 0; nn < N_; nn++) {
        if (used & (1u << nn)) continue;
        float vv = sims_s[nn];
        if (vv > best) { best = vv; bi = nn; }
      }
      used |= 1u << bi;
      sel[r * K_ + k] = nb_s[bi];
    }
    if (r == 0) *fanin = 4.0f;
  }
}

// ---------------------------------------------------------------------------
// Kernel 4: Am16[r*64+b][d] = fp16(mean_k h[sel[r][k]][b][d])  (fp32 mean)
// Grid (R, 4): 16 b-rows per block.
// ---------------------------------------------------------------------------
__global__ __launch_bounds__(256) void am_kernel(
    const float* __restrict__ h, const int* __restrict__ sel,
    _Float16* __restrict__ Am16) {
  const int r = blockIdx.x;
  const int rs = blockIdx.y * 16;
  const int t = threadIdx.x;
  __shared__ int sel_s[K_];
  if (t < K_) sel_s[t] = sel[r * K_ + t];
  __syncthreads();
  const size_t s0 = (size_t)sel_s[0] * RBD;
  const size_t s1 = (size_t)sel_s[1] * RBD;
  const size_t s2 = (size_t)sel_s[2] * RBD;
  const size_t s3 = (size_t)sel_s[3] * RBD;
  for (int i = t; i < 2048; i += 256) {
    const int row = rs + (i >> 7);
    const int c = (i & 127) * 4;
    const size_t off = (size_t)row * 512 + c;
    float4 q0 = *(const float4*)&h[s0 + off];
    float4 q1 = *(const float4*)&h[s1 + off];
    float4 q2 = *(const float4*)&h[s2 + off];
    float4 q3 = *(const float4*)&h[s3 + off];
    f16x4 m = {(_Float16)(0.25f * (q0.x + q1.x + q2.x + q3.x)),
               (_Float16)(0.25f * (q0.y + q1.y + q2.y + q3.y)),
               (_Float16)(0.25f * (q0.z + q1.z + q2.z + q3.z)),
               (_Float16)(0.25f * (q0.w + q1.w + q2.w + q3.w))};
    *(f16x4*)&Am16[((size_t)r * 64 + row) * 512 + c] = m;
  }
}

// ---------------------------------------------------------------------------
// Kernel 5: fp16 MFMA GEMM. out[m][e] = bias[e] + sum_k A[m][k]*W16[e][k]
// A: k<512 from A16[m][k], k>=512 from Am16[m][k-512]. M=16384,N=512,K=1024.
// Tile 128x128, BK=64, XOR-swizzled LDS via pre-swizzled global source.
// ---------------------------------------------------------------------------
__global__ __launch_bounds__(256) void mfma_gemm_kernel(
    const _Float16* __restrict__ A16, const _Float16* __restrict__ Am16,
    const _Float16* __restrict__ W16, const float* __restrict__ bias,
    float* __restrict__ out) {
  const int t = threadIdx.x;
  const int lane = t & 63;
  const int w = t >> 6;
  const int m0 = blockIdx.y * 128;
  const int eb = blockIdx.x * 128;
  __shared__ char smemA[128 * 128];
  __shared__ char smemW[128 * 128];
  const int wm = w >> 1, wn = w & 1;
  const int rlane = lane & 15;
  const int kq = lane >> 4;
  const int row_in_sweep = t >> 3;
  const int slot_st = t & 7;

  f32x4 acc[4][4] = {};

  const char* Ab = (const char*)A16;
  const char* Amb = (const char*)Am16;
  const char* Wb = (const char*)W16;

  for (int kt = 0; kt < 16; ++kt) {
#pragma unroll
    for (int q = 0; q < 4; ++q) {
      const int row = q * 32 + row_in_sweep;
      const int slot = slot_st ^ (row & 7);
      const char* ga =
          (kt < 8)
              ? Ab + ((size_t)(m0 + row) * 1024 + kt * 128 + slot * 16)
              : Amb + ((size_t)(m0 + row) * 1024 + (kt - 8) * 128 + slot * 16);
      const char* gw = Wb + ((size_t)(eb + row) * 2048 + kt * 128 + slot * 16);
      char* la = smemA + q * 4096 + w * 1024;
      char* lw = smemW + q * 4096 + w * 1024;
      __builtin_amdgcn_global_load_lds((const g_u32*)ga, (l_u32*)la, 16, 0, 0);
      __builtin_amdgcn_global_load_lds((const g_u32*)gw, (l_u32*)lw, 16, 0, 0);
    }
    __syncthreads();
#pragma unroll
    for (int ks = 0; ks < 2; ++ks) {
      f16x8 a[4], b[4];
#pragma unroll
      for (int i = 0; i < 4; ++i) {
        const int row = wm * 64 + i * 16 + rlane;
        const int slot = (ks * 4 + kq) ^ (row & 7);
        a[i] = *(const f16x8*)(smemA + row * 128 + slot * 16);
      }
#pragma unroll
      for (int j = 0; j < 4; ++j) {
        const int row = wn * 64 + j * 16 + rlane;
        const int slot = (ks * 4 + kq) ^ (row & 7);
        b[j] = *(const f16x8*)(smemW + row * 128 + slot * 16);
      }
#pragma unroll
      for (int i = 0; i < 4; ++i)
#pragma unroll
        for (int j = 0; j < 4; ++j)
          acc[i][j] = __builtin_amdgcn_mfma_f32_16x16x32_f16(a[i], b[j],
                                                             acc[i][j], 0, 0, 0);
    }
    __syncthreads();
  }

  float bj[4];
#pragma unroll
  for (int j = 0; j < 4; ++j) bj[j] = bias[eb + wn * 64 + j * 16 + rlane];
#pragma unroll
  for (int i = 0; i < 4; ++i) {
#pragma unroll
    for (int reg = 0; reg < 4; ++reg) {
      const size_t m = (size_t)m0 + wm * 64 + i * 16 + kq * 4 + reg;
      float* po = out + m * 512 + eb + wn * 64 + rlane;
#pragma unroll
      for (int j = 0; j < 4; ++j) po[j * 16] = acc[i][j][reg] + bj[j];
    }
  }
}

// ---------------------------------------------------------------------------
// Fallback fp32 path (small workspace): round-1 kernels.
// ---------------------------------------------------------------------------
__global__ __launch_bounds__(256) void bias_kernel(
    const float* __restrict__ Wm, const float* __restrict__ b_msg,
    const float* __restrict__ b_merge, float* __restrict__ bias_eff) {
  const int e = blockIdx.x * 256 + threadIdx.x;
  const float4* bp = (const float4*)b_msg;
  const float4* wp = (const float4*)&Wm[(size_t)e * 1024 + 512];
  float acc = 0.f;
  for (int c = 0; c < 128; c++) {
    float4 b4 = bp[c], w4 = wp[c];
    acc += b4.x * w4.x + b4.y * w4.y + b4.z * w4.z + b4.w * w4.w;
  }
  bias_eff[e] = acc + b_merge[e];
}

__global__ __launch_bounds__(256) void sims_topk_kernel(
    const float* __restrict__ h, const int* __restrict__ nbrs,
    int* __restrict__ sel, float* __restrict__ fanin) {
  const int r = blockIdx.x;
  const int t = threadIdx.x;
  const int lane = t & 63;
  const int wave = t >> 6;
  __shared__ float sims_s[N_];
  __shared__ int nb_s[N_];
  if (t < N_) nb_s[t] = nbrs[r * N_ + t];
  __syncthreads();
  const int n0 = wave * 4;
  const float4* hr  = (const float4*)(h + (size_t)r * RBD);
  const float4* hn0 = (const float4*)(h + (size_t)nb_s[n0 + 0] * RBD);
  const float4* hn1 = (const float4*)(h + (size_t)nb_s[n0 + 1] * RBD);
  const float4* hn2 = (const float4*)(h + (size_t)nb_s[n0 + 2] * RBD);
  const float4* hn3 = (const float4*)(h + (size_t)nb_s[n0 + 3] * RBD);
  float a0 = 0.f, a1 = 0.f, a2 = 0.f, a3 = 0.f;
  for (int i = lane; i < RBD / 4; i += 64) {
    float4 x = hr[i];
    float4 y0 = hn0[i], y1 = hn1[i], y2 = hn2[i], y3 = hn3[i];
    a0 += x.x * y0.x + x.y * y0.y + x.z * y0.z + x.w * y0.w;
    a1 += x.x * y1.x + x.y * y1.y + x.z * y1.z + x.w * y1.w;
    a2 += x.x * y2.x + x.y * y2.y + x.z * y2.z + x.w * y2.w;
    a3 += x.x * y3.x + x.y * y3.y + x.z * y3.z + x.w * y3.w;
  }
  float v[4] = {a0, a1, a2, a3};
#pragma unroll
  for (int n = 0; n < 4; n++) {
    float x = v[n];
#pragma unroll
    for (int off = 32; off > 0; off >>= 1) x += __shfl_down(x, off);
    if (lane == 0) sims_s[n0 + n] = x;
  }
  __syncthreads();
  if (t == 0) {
    unsigned used = 0;
#pragma unroll
    for (int k = 0; k < K_; k++) {
      float best = -3.0e38f;
      int bi = 0;
      for (int n = 0; n < N_; n++) {
        if (used & (1u << n)) continue;
        float vv = sims_s[n];
        if (vv > best) { best = vv; bi = n; }
      }
      used |= 1u << bi;
      sel[r * K_ + k] = nb_s[bi];
    }
    if (r == 0) *fanin = 4.0f;
  }
}

__global__ __launch_bounds__(256) void w2eff_f32_kernel(
    const float* __restrict__ Wm, const float* __restrict__ Wmsg,
    float* __restrict__ W2) {
  __shared__ float As[32][33];
  __shared__ float Bs[32][33];
  const int t = threadIdx.x;
  const int eb = blockIdx.y * 32;
  const int db = blockIdx.x * 32;
  const int tx = t % 16, ty = t / 16;
  const int lr = t / 8;
  const int lc = (t % 8) * 4;
  float a00 = 0.f, a01 = 0.f, a10 = 0.f, a11 = 0.f;
  for (int c0 = 0; c0 < 512; c0 += 32) {
    float4 av = *(const float4*)&Wm[(size_t)(eb + lr) * 1024 + 512 + c0 + lc];
    float4 bv = *(const float4*)&Wmsg[(size_t)(c0 + lr) * 512 + db + lc];
    As[lr][lc + 0] = av.x; As[lr][lc + 1] = av.y;
    As[lr][lc + 2] = av.z; As[lr][lc + 3] = av.w;
    Bs[lr][lc + 0] = bv.x; Bs[lr][lc + 1] = bv.y;
    Bs[lr][lc + 2] = bv.z; Bs[lr][lc + 3] = bv.w;
    __syncthreads();
#pragma unroll
    for (int kk = 0; kk < 32; kk++) {
      float x0 = As[2 * ty + 0][kk], x1 = As[2 * ty + 1][kk];
      float y0 = Bs[kk][2 * tx + 0], y1 = Bs[kk][2 * tx + 1];
      a00 += x0 * y0; a01 += x0 * y1;
      a10 += x1 * y0; a11 += x1 * y1;
    }
    __syncthreads();
  }
  W2[(size_t)(eb + 2 * ty + 0) * 512 + db + 2 * tx + 0] = a00;
  W2[(size_t)(eb + 2 * ty + 0) * 512 + db + 2 * tx + 1] = a01;
  W2[(size_t)(eb + 2 * ty + 1) * 512 + db + 2 * tx + 0] = a10;
  W2[(size_t)(eb + 2 * ty + 1) * 512 + db + 2 * tx + 1] = a11;
}

__global__ __launch_bounds__(256) void fused_gemm_f32_kernel(
    const float* __restrict__ h, const int* __restrict__ sel,
    const float* __restrict__ Wm, const float* __restrict__ W2,
    const float* __restrict__ bias_eff, float* __restrict__ out) {
  const int r = blockIdx.y;
  const int eb = blockIdx.x * 256;
  const int t = threadIdx.x;
  __shared__ float As[64][33];
  __shared__ float Ws[256][33];
  __shared__ int sel_s[K_];
  if (t < K_) sel_s[t] = sel[r * K_ + t];
  __syncthreads();
  const size_t hr = (size_t)r * RBD;
  const size_t s0 = (size_t)sel_s[0] * RBD;
  const size_t s1 = (size_t)sel_s[1] * RBD;
  const size_t s2 = (size_t)sel_s[2] * RBD;
  const size_t s3 = (size_t)sel_s[3] * RBD;
  const int tb = t % 8;
  const int te = t / 8;
  const int ab = t / 4;
  const int ac = (t % 4) * 8;
  float acc[8][8] = {};
  for (int d0 = 0; d0 < 1024; d0 += 32) {
    if (d0 < 512) {
      const float* src = h + hr + (size_t)ab * 512 + d0 + ac;
      float4 v0 = *(const float4*)(src);
      float4 v1 = *(const float4*)(src + 4);
      As[ab][ac + 0] = v0.x; As[ab][ac + 1] = v0.y;
      As[ab][ac + 2] = v0.z; As[ab][ac + 3] = v0.w;
      As[ab][ac + 4] = v1.x; As[ab][ac + 5] = v1.y;
      As[ab][ac + 6] = v1.z; As[ab][ac + 7] = v1.w;
    } else {
      const size_t off = (size_t)ab * 512 + (d0 - 512) + ac;
      const float* p0 = h + s0 + off;
      const float* p1 = h + s1 + off;
      const float* p2 = h + s2 + off;
      const float* p3 = h + s3 + off;
      float4 q0 = *(const float4*)p0, q0b = *(const float4*)(p0 + 4);
      float4 q1 = *(const float4*)p1, q1b = *(const float4*)(p1 + 4);
      float4 q2 = *(const float4*)p2, q2b = *(const float4*)(p2 + 4);
      float4 q3 = *(const float4*)p3, q3b = *(const float4*)(p3 + 4);
      As[ab][ac + 0] = 0.25f * (q0.x + q1.x + q2.x + q3.x);
      As[ab][ac + 1] = 0.25f * (q0.y + q1.y + q2.y + q3.y);
      As[ab][ac + 2] = 0.25f * (q0.z + q1.z + q2.z + q3.z);
      As[ab][ac + 3] = 0.25f * (q0.w + q1.w + q2.w + q3.w);
      As[ab][ac + 4] = 0.25f * (q0b.x + q1b.x + q2b.x + q3b.x);
      As[ab][ac + 5] = 0.25f * (q0b.y + q1b.y + q2b.y + q3b.y);
      As[ab][ac + 6] = 0.25f * (q0b.z + q1b.z + q2b.z + q3b.z);
      As[ab][ac + 7] = 0.25f * (q0b.w + q1b.w + q2b.w + q3b.w);
    }
    {
      const float* src = (d0 < 512)
          ? (Wm + (size_t)(eb + t) * 1024 + d0)
          : (W2 + (size_t)(eb + t) * 512 + (d0 - 512));
#pragma unroll
      for (int j = 0; j < 8; j++) {
        float4 v = *(const float4*)(src + 4 * j);
        Ws[t][4 * j + 0] = v.x; Ws[t][4 * j + 1] = v.y;
        Ws[t][4 * j + 2] = v.z; Ws[t][4 * j + 3] = v.w;
      }
    }
    __syncthreads();
#pragma unroll
    for (int kk = 0; kk < 32; kk++) {
      float a[8], wv[8];
#pragma unroll
      for (int i = 0; i < 8; i++) a[i] = As[tb + 8 * i][kk];
#pragma unroll
      for (int j = 0; j < 8; j++) wv[j] = Ws[te + 32 * j][kk];
#pragma unroll
      for (int i = 0; i < 8; i++)
#pragma unroll
        for (int j = 0; j < 8; j++) acc[i][j] += a[i] * wv[j];
    }
    __syncthreads();
  }
  float be[8];
#pragma unroll
  for (int j = 0; j < 8; j++) be[j] = bias_eff[eb + te + 32 * j];
#pragma unroll
  for (int i = 0; i < 8; i++) {
    const int b = tb + 8 * i;
#pragma unroll
    for (int j = 0; j < 8; j++) {
      const int e = eb + te + 32 * j;
      out[hr + (size_t)b * 512 + e] = acc[i][j] + be[j];
    }
  }
}

// ---------------------------------------------------------------------------
extern "C" void kernel_launch(void* const* d_in, const int* in_sizes, int n_in,
                              void* d_out, int out_size, void* d_ws,
                              size_t ws_size, hipStream_t stream) {
  const float* h       = (const float*)d_in[0];
  const int*   nbrs    = (const int*)d_in[1];
  const float* W_msg   = (const float*)d_in[2];
  const float* b_msg   = (const float*)d_in[3];
  const float* W_merge = (const float*)d_in[4];
  const float* b_merge = (const float*)d_in[5];
  float* out = (float*)d_out;
  char* ws = (char*)d_ws;

  const size_t SZ_PART = (size_t)GSLICES * 256 * 256 * 4;  // 16.78 MB each
  const size_t SZ_A = (size_t)M_TOT * 512 * 2;             // 16.78 MB each
  const size_t SZ_W = (size_t)512 * 1024 * 2;              // 1 MB
  size_t off = 0;
  int*      sel      = (int*)(ws + off);      off += 4096;
  float*    bias_eff = (float*)(ws + off);    off += 4096;
  float*    C1p      = (float*)(ws + off);    off += SZ_PART;
  float*    C2p      = (float*)(ws + off);    off += SZ_PART;
  _Float16* A16      = (_Float16*)(ws + off); off += SZ_A;
  _Float16* Alo16    = (_Float16*)(ws + off); off += SZ_A;
  _Float16* Am16     = (_Float16*)(ws + off); off += SZ_A;
  _Float16* W16      = (_Float16*)(ws + off); off += SZ_W;
  const size_t NEED = off;

  if (ws_size >= NEED) {
    prep_kernel<<<PREP_TOTAL, 256, 0, stream>>>(h, W_msg, b_msg, W_merge,
                                                b_merge, A16, Alo16, W16,
                                                bias_eff);
    gram_kernel<<<dim3(2, 2, GSLICES), 256, 0, stream>>>(A16, Alo16, C1p, C2p);
    reduce_topk_kernel<<<R_, 64, 0, stream>>>(C1p, C2p, nbrs, sel,
                                              out + OUT_ELEMS);
    am_kernel<<<dim3(R_, 4), 256, 0, stream>>>(h, sel, Am16);
    mfma_gemm_kernel<<<dim3(4, 128), 256, 0, stream>>>(A16, Am16, W16,
                                                       bias_eff, out);
  } else {
    int*   fsel     = (int*)ws;
    float* W2       = (float*)(ws + 4096);
    float* fbias    = (float*)(ws + 4096 + 512 * 512 * 4);
    sims_topk_kernel<<<R_, 256, 0, stream>>>(h, nbrs, fsel, out + OUT_ELEMS);
    bias_kernel<<<2, 256, 0, stream>>>(W_merge, b_msg, b_merge, fbias);
    w2eff_f32_kernel<<<dim3(16, 16), 256, 0, stream>>>(W_merge, W_msg, W2);
    fused_gemm_f32_kernel<<<dim3(2, R_), 256, 0, stream>>>(h, fsel, W_merge,
                                                           W2, fbias, out);
  }
}

// Round 5
// 115.219 us; speedup vs baseline: 1.1798x; 1.1798x over previous
//
#include <hip/hip_runtime.h>
#include <hip/hip_bf16.h>

#define R_ 256
#define B_ 64
#define D_ 512
#define N_ 16
#define K_ 4
#define RBD (B_ * D_)          // 32768 floats per region
#define OUT_ELEMS (R_ * B_ * D_)
#define M_TOT (R_ * B_)        // 16384
#define GSLICES 64             // gram split-K slices (K-chunk 512)

typedef __attribute__((address_space(1))) unsigned int g_u32;
typedef __attribute__((address_space(3))) unsigned int l_u32;
using f32x4 = __attribute__((ext_vector_type(4))) float;
using f16x8 = __attribute__((ext_vector_type(8))) _Float16;
using f16x4 = __attribute__((ext_vector_type(4))) _Float16;

// ---------------------------------------------------------------------------
// Kernel 1 (conv): grid-stride conversions + tiny tails.
//  - blocks [0, 2048):    h -> A16 = fp16(h), Alo16 = fp16(h - A16); 4 f4/thr
//  - blocks [2048, 2304): W16[e][d] = fp16(Wm[e][d]), d < 512
//  - blocks [2304, 2306): bias_eff[e] = b_merge[e] + b_msg . Wm2[e]
// ---------------------------------------------------------------------------
#define CONV_BLKS 2048
#define CONV_WC (CONV_BLKS + 256)
#define CONV_TOTAL (CONV_WC + 2)

__global__ __launch_bounds__(256) void conv_kernel(
    const float* __restrict__ h, const float* __restrict__ b_msg,
    const float* __restrict__ Wm, const float* __restrict__ b_merge,
    _Float16* __restrict__ A16, _Float16* __restrict__ Alo16,
    _Float16* __restrict__ W16, float* __restrict__ bias_eff) {
  const int bx = blockIdx.x;
  const int t = threadIdx.x;
  if (bx < CONV_BLKS) {
#pragma unroll
    for (int it = 0; it < 4; ++it) {
      const int i = bx * 256 + t + it * (CONV_BLKS * 256);  // float4 id
      float4 v = *(const float4*)&h[(size_t)i * 4];
      _Float16 hx = (_Float16)v.x, hy = (_Float16)v.y;
      _Float16 hz = (_Float16)v.z, hw = (_Float16)v.w;
      f16x4 hi = {hx, hy, hz, hw};
      f16x4 lo = {(_Float16)(v.x - (float)hx), (_Float16)(v.y - (float)hy),
                  (_Float16)(v.z - (float)hz), (_Float16)(v.w - (float)hw)};
      *(f16x4*)&A16[(size_t)i * 4] = hi;
      *(f16x4*)&Alo16[(size_t)i * 4] = lo;
    }
  } else if (bx < CONV_WC) {
    const int i = (bx - CONV_BLKS) * 256 + t;  // 0..65535 float4 ids
    const int e = i >> 7;
    const int c4 = (i & 127) * 4;
    float4 v = *(const float4*)&Wm[(size_t)e * 1024 + c4];
    f16x4 o = {(_Float16)v.x, (_Float16)v.y, (_Float16)v.z, (_Float16)v.w};
    *(f16x4*)&W16[(size_t)e * 1024 + c4] = o;
  } else {
    const int e = (bx - CONV_WC) * 256 + t;  // 0..511
    const float4* bp = (const float4*)b_msg;
    const float4* wp = (const float4*)&Wm[(size_t)e * 1024 + 512];
    float acc = 0.f;
    for (int c = 0; c < 128; c++) {
      float4 b4 = bp[c], w4 = wp[c];
      acc += b4.x * w4.x + b4.y * w4.y + b4.z * w4.z + b4.w * w4.w;
    }
    bias_eff[e] = acc + b_merge[e];
  }
}

// ---------------------------------------------------------------------------
// Kernel 2 (wsplit): W2p[kc][e][d] = sum_{c in kc-chunk} Wm2[e][c]*Wmsg[c][d]
// Grid (16,16,4) = 1024 blocks, K-chunk 128 -> 4 c0-iterations per block.
// ---------------------------------------------------------------------------
__global__ __launch_bounds__(256) void wsplit_kernel(
    const float* __restrict__ Wm, const float* __restrict__ Wmsg,
    float* __restrict__ W2p) {
  __shared__ float As[32][33];
  __shared__ float Bs[32][33];
  const int t = threadIdx.x;
  const int db = blockIdx.x * 32;
  const int eb = blockIdx.y * 32;
  const int kc = blockIdx.z;
  const int tx = t % 16, ty = t / 16;
  const int lr = t / 8;
  const int lc = (t % 8) * 4;
  float a00 = 0.f, a01 = 0.f, a10 = 0.f, a11 = 0.f;
  for (int c0 = kc * 128; c0 < kc * 128 + 128; c0 += 32) {
    float4 av = *(const float4*)&Wm[(size_t)(eb + lr) * 1024 + 512 + c0 + lc];
    float4 bv = *(const float4*)&Wmsg[(size_t)(c0 + lr) * 512 + db + lc];
    As[lr][lc + 0] = av.x; As[lr][lc + 1] = av.y;
    As[lr][lc + 2] = av.z; As[lr][lc + 3] = av.w;
    Bs[lr][lc + 0] = bv.x; Bs[lr][lc + 1] = bv.y;
    Bs[lr][lc + 2] = bv.z; Bs[lr][lc + 3] = bv.w;
    __syncthreads();
#pragma unroll
    for (int kk = 0; kk < 32; kk++) {
      float x0 = As[2 * ty + 0][kk], x1 = As[2 * ty + 1][kk];
      float y0 = Bs[kk][2 * tx + 0], y1 = Bs[kk][2 * tx + 1];
      a00 += x0 * y0; a01 += x0 * y1;
      a10 += x1 * y0; a11 += x1 * y1;
    }
    __syncthreads();
  }
  float* base = W2p + (size_t)kc * 512 * 512;
  base[(size_t)(eb + 2 * ty + 0) * 512 + db + 2 * tx + 0] = a00;
  base[(size_t)(eb + 2 * ty + 0) * 512 + db + 2 * tx + 1] = a01;
  base[(size_t)(eb + 2 * ty + 1) * 512 + db + 2 * tx + 0] = a10;
  base[(size_t)(eb + 2 * ty + 1) * 512 + db + 2 * tx + 1] = a11;
}

// ---------------------------------------------------------------------------
// Kernel 3 (w2fin): W16[e][512+d] = fp16(sum_kc W2p[kc][e][d]), fixed order.
// ---------------------------------------------------------------------------
__global__ __launch_bounds__(256) void w2fin_kernel(
    const float* __restrict__ W2p, _Float16* __restrict__ W16) {
  const int i = blockIdx.x * 256 + threadIdx.x;  // 0..262143
  const int e = i >> 9;
  const int d = i & 511;
  float acc = 0.f;
#pragma unroll
  for (int kc = 0; kc < 4; ++kc)
    acc += W2p[(size_t)kc * 512 * 512 + (size_t)e * 512 + d];
  W16[(size_t)e * 1024 + 512 + d] = (_Float16)acc;
}

// ---------------------------------------------------------------------------
// Kernel 4 (gram): split-precision Gram partials via fp16 MFMA.
//   C1p[s] = Hi_I . Hi_J^T ; C2p[s] = Hi_I . Lo_J^T   over K-chunk s (512).
// Grid (2,2,GSLICES). 128x128 tile, BK=64, 4 waves 2x2, XOR-swizzled LDS
// via pre-swizzled global source (linear gload_lds dest).
// ---------------------------------------------------------------------------
__global__ __launch_bounds__(256) void gram_kernel(
    const _Float16* __restrict__ Hi, const _Float16* __restrict__ Lo,
    float* __restrict__ C1p, float* __restrict__ C2p) {
  const int t = threadIdx.x;
  const int lane = t & 63;
  const int w = t >> 6;
  const int I = blockIdx.x * 128;
  const int J = blockIdx.y * 128;
  const int s = blockIdx.z;
  __shared__ char sHiI[128 * 128];
  __shared__ char sHiJ[128 * 128];
  __shared__ char sLoJ[128 * 128];
  const int wm = w >> 1, wn = w & 1;
  const int rlane = lane & 15;
  const int kq = lane >> 4;
  const int row_in_sweep = t >> 3;
  const int slot_st = t & 7;

  f32x4 c1[4][4] = {};
  f32x4 c2[4][4] = {};

  const char* HiB = (const char*)Hi;
  const char* LoB = (const char*)Lo;
  const size_t kbase = (size_t)s * 1024;  // bytes: s * 512 elems * 2B

  for (int it = 0; it < 8; ++it) {
#pragma unroll
    for (int q = 0; q < 4; ++q) {
      const int row = q * 32 + row_in_sweep;
      const int slot = slot_st ^ (row & 7);
      const size_t koff = kbase + it * 128 + slot * 16;
      const char* gi = HiB + (size_t)(I + row) * 65536 + koff;
      const char* gj = HiB + (size_t)(J + row) * 65536 + koff;
      const char* gl = LoB + (size_t)(J + row) * 65536 + koff;
      char* di = sHiI + q * 4096 + w * 1024;
      char* dj = sHiJ + q * 4096 + w * 1024;
      char* dl = sLoJ + q * 4096 + w * 1024;
      __builtin_amdgcn_global_load_lds((const g_u32*)gi, (l_u32*)di, 16, 0, 0);
      __builtin_amdgcn_global_load_lds((const g_u32*)gj, (l_u32*)dj, 16, 0, 0);
      __builtin_amdgcn_global_load_lds((const g_u32*)gl, (l_u32*)dl, 16, 0, 0);
    }
    __syncthreads();
#pragma unroll
    for (int ks = 0; ks < 2; ++ks) {
      f16x8 ai[4], bj[4], lj[4];
#pragma unroll
      for (int i = 0; i < 4; ++i) {
        const int row = wm * 64 + i * 16 + rlane;
        const int slot = (ks * 4 + kq) ^ (row & 7);
        ai[i] = *(const f16x8*)(sHiI + row * 128 + slot * 16);
      }
#pragma unroll
      for (int j = 0; j < 4; ++j) {
        const int row = wn * 64 + j * 16 + rlane;
        const int slot = (ks * 4 + kq) ^ (row & 7);
        bj[j] = *(const f16x8*)(sHiJ + row * 128 + slot * 16);
        lj[j] = *(const f16x8*)(sLoJ + row * 128 + slot * 16);
      }
#pragma unroll
      for (int i = 0; i < 4; ++i)
#pragma unroll
        for (int j = 0; j < 4; ++j) {
          c1[i][j] = __builtin_amdgcn_mfma_f32_16x16x32_f16(ai[i], bj[j],
                                                            c1[i][j], 0, 0, 0);
          c2[i][j] = __builtin_amdgcn_mfma_f32_16x16x32_f16(ai[i], lj[j],
                                                            c2[i][j], 0, 0, 0);
        }
    }
    __syncthreads();
  }

#pragma unroll
  for (int i = 0; i < 4; ++i) {
#pragma unroll
    for (int reg = 0; reg < 4; ++reg) {
      const int gr = I + wm * 64 + i * 16 + kq * 4 + reg;
      const size_t base = ((size_t)s * 256 + gr) * 256 + J + wn * 64 + rlane;
      float* p1 = C1p + base;
      float* p2 = C2p + base;
#pragma unroll
      for (int j = 0; j < 4; ++j) {
        p1[j * 16] = c1[i][j][reg];
        p2[j * 16] = c2[i][j][reg];
      }
    }
  }
}

// ---------------------------------------------------------------------------
// Kernel 5: reduce partials in fixed order -> sims; stable top-4 (strict >,
// first index wins = jax.lax.top_k tie rule). 256 thr: 16 lanes per neighbor.
// G[r][j] = sum_s C1p[s][r][j] + C2p[s][r][j] + C2p[s][j][r]
// ---------------------------------------------------------------------------
__global__ __launch_bounds__(256) void reduce_topk_kernel(
    const float* __restrict__ C1p, const float* __restrict__ C2p,
    const int* __restrict__ nbrs, int* __restrict__ sel,
    float* __restrict__ fanin) {
  const int r = blockIdx.x;
  const int t = threadIdx.x;
  const int n = t >> 4;       // 0..15
  const int sq = t & 15;      // 0..15
  __shared__ float sims_s[N_];
  __shared__ int nb_s[N_];
  if (t < N_) nb_s[t] = nbrs[r * N_ + t];
  __syncthreads();
  const int j = nb_s[n];
  float acc = 0.f;
  // slices sq*4 .. sq*4+3, fixed order within and across lanes
#pragma unroll
  for (int s = sq * 4; s < sq * 4 + 4; ++s) {
    const size_t rj = ((size_t)s * 256 + r) * 256 + j;
    const size_t jr = ((size_t)s * 256 + j) * 256 + r;
    acc += C1p[rj] + C2p[rj] + C2p[jr];
  }
  acc += __shfl_xor(acc, 1);
  acc += __shfl_xor(acc, 2);
  acc += __shfl_xor(acc, 4);
  acc += __shfl_xor(acc, 8);
  if (sq == 0) sims_s[n] = acc;
  __syncthreads();
  if (t == 0) {
    unsigned used = 0;
#pragma unroll
    for (int k = 0; k < K_; k++) {
      float best = -3.0e38f;
      int bi = 0;
      for (int nn = 0; nn < N_; nn++) {
        if (used & (1u << nn)) continue;
        float vv = sims_s[nn];
        if (vv > best) { best = vv; bi = nn; }
      }
      used |= 1u << bi;
      sel[r * K_ + k] = nb_s[bi];
    }
    if (r == 0) *fanin = 4.0f;
  }
}

// ---------------------------------------------------------------------------
// Kernel 6: Am16[r*64+b][d] = fp16(mean_k A16[sel[r][k]][b][d])  (fp32 mean)
// Grid (R, 4): 16 b-rows per block; sources fp16 (half the read traffic).
// ---------------------------------------------------------------------------
__global__ __launch_bounds__(256) void am_kernel(
    const _Float16* __restrict__ A16, const int* __restrict__ sel,
    _Float16* __restrict__ Am16) {
  const int r = blockIdx.x;
  const int rs = blockIdx.y * 16;
  const int t = threadIdx.x;
  __shared__ int sel_s[K_];
  if (t < K_) sel_s[t] = sel[r * K_ + t];
  __syncthreads();
  const size_t s0 = (size_t)sel_s[0] * RBD;
  const size_t s1 = (size_t)sel_s[1] * RBD;
  const size_t s2 = (size_t)sel_s[2] * RBD;
  const size_t s3 = (size_t)sel_s[3] * RBD;
  for (int i = t; i < 1024; i += 256) {
    const int row = rs + (i >> 6);
    const int c = (i & 63) * 8;
    const size_t off = (size_t)row * 512 + c;
    f16x8 q0 = *(const f16x8*)&A16[s0 + off];
    f16x8 q1 = *(const f16x8*)&A16[s1 + off];
    f16x8 q2 = *(const f16x8*)&A16[s2 + off];
    f16x8 q3 = *(const f16x8*)&A16[s3 + off];
    f16x8 m;
#pragma unroll
    for (int e = 0; e < 8; ++e)
      m[e] = (_Float16)(0.25f * ((float)q0[e] + (float)q1[e] + (float)q2[e] +
                                 (float)q3[e]));
    *(f16x8*)&Am16[((size_t)r * 64 + row) * 512 + c] = m;
  }
}

// ---------------------------------------------------------------------------
// Kernel 7: fp16 MFMA GEMM. out[m][e] = bias[e] + sum_k A[m][k]*W16[e][k]
// A: k<512 from A16[m][k], k>=512 from Am16[m][k-512]. M=16384,N=512,K=1024.
// ---------------------------------------------------------------------------
__global__ __launch_bounds__(256) void mfma_gemm_kernel(
    const _Float16* __restrict__ A16, const _Float16* __restrict__ Am16,
    const _Float16* __restrict__ W16, const float* __restrict__ bias,
    float* __restrict__ out) {
  const int t = threadIdx.x;
  const int lane = t & 63;
  const int w = t >> 6;
  const int m0 = blockIdx.y * 128;
  const int eb = blockIdx.x * 128;
  __shared__ char smemA[128 * 128];
  __shared__ char smemW[128 * 128];
  const int wm = w >> 1, wn = w & 1;
  const int rlane = lane & 15;
  const int kq = lane >> 4;
  const int row_in_sweep = t >> 3;
  const int slot_st = t & 7;

  f32x4 acc[4][4] = {};

  const char* Ab = (const char*)A16;
  const char* Amb = (const char*)Am16;
  const char* Wb = (const char*)W16;

  for (int kt = 0; kt < 16; ++kt) {
#pragma unroll
    for (int q = 0; q < 4; ++q) {
      const int row = q * 32 + row_in_sweep;
      const int slot = slot_st ^ (row & 7);
      const char* ga =
          (kt < 8)
              ? Ab + ((size_t)(m0 + row) * 1024 + kt * 128 + slot * 16)
              : Amb + ((size_t)(m0 + row) * 1024 + (kt - 8) * 128 + slot * 16);
      const char* gw = Wb + ((size_t)(eb + row) * 2048 + kt * 128 + slot * 16);
      char* la = smemA + q * 4096 + w * 1024;
      char* lw = smemW + q * 4096 + w * 1024;
      __builtin_amdgcn_global_load_lds((const g_u32*)ga, (l_u32*)la, 16, 0, 0);
      __builtin_amdgcn_global_load_lds((const g_u32*)gw, (l_u32*)lw, 16, 0, 0);
    }
    __syncthreads();
#pragma unroll
    for (int ks = 0; ks < 2; ++ks) {
      f16x8 a[4], b[4];
#pragma unroll
      for (int i = 0; i < 4; ++i) {
        const int row = wm * 64 + i * 16 + rlane;
        const int slot = (ks * 4 + kq) ^ (row & 7);
        a[i] = *(const f16x8*)(smemA + row * 128 + slot * 16);
      }
#pragma unroll
      for (int j = 0; j < 4; ++j) {
        const int row = wn * 64 + j * 16 + rlane;
        const int slot = (ks * 4 + kq) ^ (row & 7);
        b[j] = *(const f16x8*)(smemW + row * 128 + slot * 16);
      }
#pragma unroll
      for (int i = 0; i < 4; ++i)
#pragma unroll
        for (int j = 0; j < 4; ++j)
          acc[i][j] = __builtin_amdgcn_mfma_f32_16x16x32_f16(a[i], b[j],
                                                             acc[i][j], 0, 0, 0);
    }
    __syncthreads();
  }

  float bj[4];
#pragma unroll
  for (int j = 0; j < 4; ++j) bj[j] = bias[eb + wn * 64 + j * 16 + rlane];
#pragma unroll
  for (int i = 0; i < 4; ++i) {
#pragma unroll
    for (int reg = 0; reg < 4; ++reg) {
      const size_t m = (size_t)m0 + wm * 64 + i * 16 + kq * 4 + reg;
      float* po = out + m * 512 + eb + wn * 64 + rlane;
#pragma unroll
      for (int j = 0; j < 4; ++j) po[j * 16] = acc[i][j][reg] + bj[j];
    }
  }
}

// ---------------------------------------------------------------------------
// Fallback fp32 path (small workspace): round-1 kernels.
// ---------------------------------------------------------------------------
__global__ __launch_bounds__(256) void bias_kernel(
    const float* __restrict__ Wm, const float* __restrict__ b_msg,
    const float* __restrict__ b_merge, float* __restrict__ bias_eff) {
  const int e = blockIdx.x * 256 + threadIdx.x;
  const float4* bp = (const float4*)b_msg;
  const float4* wp = (const float4*)&Wm[(size_t)e * 1024 + 512];
  float acc = 0.f;
  for (int c = 0; c < 128; c++) {
    float4 b4 = bp[c], w4 = wp[c];
    acc += b4.x * w4.x + b4.y * w4.y + b4.z * w4.z + b4.w * w4.w;
  }
  bias_eff[e] = acc + b_merge[e];
}

__global__ __launch_bounds__(256) void sims_topk_kernel(
    const float* __restrict__ h, const int* __restrict__ nbrs,
    int* __restrict__ sel, float* __restrict__ fanin) {
  const int r = blockIdx.x;
  const int t = threadIdx.x;
  const int lane = t & 63;
  const int wave = t >> 6;
  __shared__ float sims_s[N_];
  __shared__ int nb_s[N_];
  if (t < N_) nb_s[t] = nbrs[r * N_ + t];
  __syncthreads();
  const int n0 = wave * 4;
  const float4* hr  = (const float4*)(h + (size_t)r * RBD);
  const float4* hn0 = (const float4*)(h + (size_t)nb_s[n0 + 0] * RBD);
  const float4* hn1 = (const float4*)(h + (size_t)nb_s[n0 + 1] * RBD);
  const float4* hn2 = (const float4*)(h + (size_t)nb_s[n0 + 2] * RBD);
  const float4* hn3 = (const float4*)(h + (size_t)nb_s[n0 + 3] * RBD);
  float a0 = 0.f, a1 = 0.f, a2 = 0.f, a3 = 0.f;
  for (int i = lane; i < RBD / 4; i += 64) {
    float4 x = hr[i];
    float4 y0 = hn0[i], y1 = hn1[i], y2 = hn2[i], y3 = hn3[i];
    a0 += x.x * y0.x + x.y * y0.y + x.z * y0.z + x.w * y0.w;
    a1 += x.x * y1.x + x.y * y1.y + x.z * y1.z + x.w * y1.w;
    a2 += x.x * y2.x + x.y * y2.y + x.z * y2.z + x.w * y2.w;
    a3 += x.x * y3.x + x.y * y3.y + x.z * y3.z + x.w * y3.w;
  }
  float v[4] = {a0, a1, a2, a3};
#pragma unroll
  for (int n = 0; n < 4; n++) {
    float x = v[n];
#pragma unroll
    for (int off = 32; off > 0; off >>= 1) x += __shfl_down(x, off);
    if (lane == 0) sims_s[n0 + n] = x;
  }
  __syncthreads();
  if (t == 0) {
    unsigned used = 0;
#pragma unroll
    for (int k = 0; k < K_; k++) {
      float best = -3.0e38f;
      int bi = 0;
      for (int n = 0; n < N_; n++) {
        if (used & (1u << n)) continue;
        float vv = sims_s[n];
        if (vv > best) { best = vv; bi = n; }
      }
      used |= 1u << bi;
      sel[r * K_ + k] = nb_s[bi];
    }
    if (r == 0) *fanin = 4.0f;
  }
}

__global__ __launch_bounds__(256) void w2eff_f32_kernel(
    const float* __restrict__ Wm, const float* __restrict__ Wmsg,
    float* __restrict__ W2) {
  __shared__ float As[32][33];
  __shared__ float Bs[32][33];
  const int t = threadIdx.x;
  const int eb = blockIdx.y * 32;
  const int db = blockIdx.x * 32;
  const int tx = t % 16, ty = t / 16;
  const int lr = t / 8;
  const int lc = (t % 8) * 4;
  float a00 = 0.f, a01 = 0.f, a10 = 0.f, a11 = 0.f;
  for (int c0 = 0; c0 < 512; c0 += 32) {
    float4 av = *(const float4*)&Wm[(size_t)(eb + lr) * 1024 + 512 + c0 + lc];
    float4 bv = *(const float4*)&Wmsg[(size_t)(c0 + lr) * 512 + db + lc];
    As[lr][lc + 0] = av.x; As[lr][lc + 1] = av.y;
    As[lr][lc + 2] = av.z; As[lr][lc + 3] = av.w;
    Bs[lr][lc + 0] = bv.x; Bs[lr][lc + 1] = bv.y;
    Bs[lr][lc + 2] = bv.z; Bs[lr][lc + 3] = bv.w;
    __syncthreads();
#pragma unroll
    for (int kk = 0; kk < 32; kk++) {
      float x0 = As[2 * ty + 0][kk], x1 = As[2 * ty + 1][kk];
      float y0 = Bs[kk][2 * tx + 0], y1 = Bs[kk][2 * tx + 1];
      a00 += x0 * y0; a01 += x0 * y1;
      a10 += x1 * y0; a11 += x1 * y1;
    }
    __syncthreads();
  }
  W2[(size_t)(eb + 2 * ty + 0) * 512 + db + 2 * tx + 0] = a00;
  W2[(size_t)(eb + 2 * ty + 0) * 512 + db + 2 * tx + 1] = a01;
  W2[(size_t)(eb + 2 * ty + 1) * 512 + db + 2 * tx + 0] = a10;
  W2[(size_t)(eb + 2 * ty + 1) * 512 + db + 2 * tx + 1] = a11;
}

__global__ __launch_bounds__(256) void fused_gemm_f32_kernel(
    const float* __restrict__ h, const int* __restrict__ sel,
    const float* __restrict__ Wm, const float* __restrict__ W2,
    const float* __restrict__ bias_eff, float* __restrict__ out) {
  const int r = blockIdx.y;
  const int eb = blockIdx.x * 256;
  const int t = threadIdx.x;
  __shared__ float As[64][33];
  __shared__ float Ws[256][33];
  __shared__ int sel_s[K_];
  if (t < K_) sel_s[t] = sel[r * K_ + t];
  __syncthreads();
  const size_t hr = (size_t)r * RBD;
  const size_t s0 = (size_t)sel_s[0] * RBD;
  const size_t s1 = (size_t)sel_s[1] * RBD;
  const size_t s2 = (size_t)sel_s[2] * RBD;
  const size_t s3 = (size_t)sel_s[3] * RBD;
  const int tb = t % 8;
  const int te = t / 8;
  const int ab = t / 4;
  const int ac = (t % 4) * 8;
  float acc[8][8] = {};
  for (int d0 = 0; d0 < 1024; d0 += 32) {
    if (d0 < 512) {
      const float* src = h + hr + (size_t)ab * 512 + d0 + ac;
      float4 v0 = *(const float4*)(src);
      float4 v1 = *(const float4*)(src + 4);
      As[ab][ac + 0] = v0.x; As[ab][ac + 1] = v0.y;
      As[ab][ac + 2] = v0.z; As[ab][ac + 3] = v0.w;
      As[ab][ac + 4] = v1.x; As[ab][ac + 5] = v1.y;
      As[ab][ac + 6] = v1.z; As[ab][ac + 7] = v1.w;
    } else {
      const size_t off = (size_t)ab * 512 + (d0 - 512) + ac;
      const float* p0 = h + s0 + off;
      const float* p1 = h + s1 + off;
      const float* p2 = h + s2 + off;
      const float* p3 = h + s3 + off;
      float4 q0 = *(const float4*)p0, q0b = *(const float4*)(p0 + 4);
      float4 q1 = *(const float4*)p1, q1b = *(const float4*)(p1 + 4);
      float4 q2 = *(const float4*)p2, q2b = *(const float4*)(p2 + 4);
      float4 q3 = *(const float4*)p3, q3b = *(const float4*)(p3 + 4);
      As[ab][ac + 0] = 0.25f * (q0.x + q1.x + q2.x + q3.x);
      As[ab][ac + 1] = 0.25f * (q0.y + q1.y + q2.y + q3.y);
      As[ab][ac + 2] = 0.25f * (q0.z + q1.z + q2.z + q3.z);
      As[ab][ac + 3] = 0.25f * (q0.w + q1.w + q2.w + q3.w);
      As[ab][ac + 4] = 0.25f * (q0b.x + q1b.x + q2b.x + q3b.x);
      As[ab][ac + 5] = 0.25f * (q0b.y + q1b.y + q2b.y + q3b.y);
      As[ab][ac + 6] = 0.25f * (q0b.z + q1b.z + q2b.z + q3b.z);
      As[ab][ac + 7] = 0.25f * (q0b.w + q1b.w + q2b.w + q3b.w);
    }
    {
      const float* src = (d0 < 512)
          ? (Wm + (size_t)(eb + t) * 1024 + d0)
          : (W2 + (size_t)(eb + t) * 512 + (d0 - 512));
#pragma unroll
      for (int j = 0; j < 8; j++) {
        float4 v = *(const float4*)(src + 4 * j);
        Ws[t][4 * j + 0] = v.x; Ws[t][4 * j + 1] = v.y;
        Ws[t][4 * j + 2] = v.z; Ws[t][4 * j + 3] = v.w;
      }
    }
    __syncthreads();
#pragma unroll
    for (int kk = 0; kk < 32; kk++) {
      float a[8], wv[8];
#pragma unroll
      for (int i = 0; i < 8; i++) a[i] = As[tb + 8 * i][kk];
#pragma unroll
      for (int j = 0; j < 8; j++) wv[j] = Ws[te + 32 * j][kk];
#pragma unroll
      for (int i = 0; i < 8; i++)
#pragma unroll
        for (int j = 0; j < 8; j++) acc[i][j] += a[i] * wv[j];
    }
    __syncthreads();
  }
  float be[8];
#pragma unroll
  for (int j = 0; j < 8; j++) be[j] = bias_eff[eb + te + 32 * j];
#pragma unroll
  for (int i = 0; i < 8; i++) {
    const int b = tb + 8 * i;
#pragma unroll
    for (int j = 0; j < 8; j++) {
      const int e = eb + te + 32 * j;
      out[hr + (size_t)b * 512 + e] = acc[i][j] + be[j];
    }
  }
}

// ---------------------------------------------------------------------------
extern "C" void kernel_launch(void* const* d_in, const int* in_sizes, int n_in,
                              void* d_out, int out_size, void* d_ws,
                              size_t ws_size, hipStream_t stream) {
  const float* h       = (const float*)d_in[0];
  const int*   nbrs    = (const int*)d_in[1];
  const float* W_msg   = (const float*)d_in[2];
  const float* b_msg   = (const float*)d_in[3];
  const float* W_merge = (const float*)d_in[4];
  const float* b_merge = (const float*)d_in[5];
  float* out = (float*)d_out;
  char* ws = (char*)d_ws;

  const size_t SZ_PART = (size_t)GSLICES * 256 * 256 * 4;  // 16.78 MB each
  const size_t SZ_A = (size_t)M_TOT * 512 * 2;             // 16.78 MB each
  const size_t SZ_W = (size_t)512 * 1024 * 2;              // 1 MB
  size_t off = 0;
  int*      sel      = (int*)(ws + off);      off += 4096;
  float*    bias_eff = (float*)(ws + off);    off += 4096;
  float*    C1p      = (float*)(ws + off);    off += SZ_PART;
  float*    C2p      = (float*)(ws + off);    off += SZ_PART;
  _Float16* A16      = (_Float16*)(ws + off); off += SZ_A;
  _Float16* Alo16    = (_Float16*)(ws + off); off += SZ_A;
  _Float16* Am16     = (_Float16*)(ws + off); off += SZ_A;
  _Float16* W16      = (_Float16*)(ws + off); off += SZ_W;
  const size_t NEED = off;
  // W2p (4 MB) aliases C1p: consumed by w2fin before gram writes C1p.
  float* W2p = C1p;

  if (ws_size >= NEED) {
    conv_kernel<<<CONV_TOTAL, 256, 0, stream>>>(h, b_msg, W_merge, b_merge,
                                                A16, Alo16, W16, bias_eff);
    wsplit_kernel<<<dim3(16, 16, 4), 256, 0, stream>>>(W_merge, W_msg, W2p);
    w2fin_kernel<<<1024, 256, 0, stream>>>(W2p, W16);
    gram_kernel<<<dim3(2, 2, GSLICES), 256, 0, stream>>>(A16, Alo16, C1p, C2p);
    reduce_topk_kernel<<<R_, 256, 0, stream>>>(C1p, C2p, nbrs, sel,
                                               out + OUT_ELEMS);
    am_kernel<<<dim3(R_, 4), 256, 0, stream>>>(A16, sel, Am16);
    mfma_gemm_kernel<<<dim3(4, 128), 256, 0, stream>>>(A16, Am16, W16,
                                                       bias_eff, out);
  } else {
    int*   fsel     = (int*)ws;
    float* W2       = (float*)(ws + 4096);
    float* fbias    = (float*)(ws + 4096 + 512 * 512 * 4);
    sims_topk_kernel<<<R_, 256, 0, stream>>>(h, nbrs, fsel, out + OUT_ELEMS);
    bias_kernel<<<2, 256, 0, stream>>>(W_merge, b_msg, b_merge, fbias);
    w2eff_f32_kernel<<<dim3(16, 16), 256, 0, stream>>>(W_merge, W_msg, W2);
    fused_gemm_f32_kernel<<<dim3(2, R_), 256, 0, stream>>>(h, fsel, W_merge,
                                                           W2, fbias, out);
  }
}

// Round 6
// 105.031 us; speedup vs baseline: 1.2942x; 1.0970x over previous
//
#include <hip/hip_runtime.h>
#include <hip/hip_bf16.h>

#define R_ 256
#define B_ 64
#define D_ 512
#define N_ 16
#define K_ 4
#define RBD (B_ * D_)          // 32768 floats per region
#define OUT_ELEMS (R_ * B_ * D_)
#define M_TOT (R_ * B_)        // 16384
#define GSLICES 64             // gram split-K slices (K-chunk 512 fp32)

typedef __attribute__((address_space(1))) unsigned int g_u32;
typedef __attribute__((address_space(3))) unsigned int l_u32;
using f32x4 = __attribute__((ext_vector_type(4))) float;
using f16x8 = __attribute__((ext_vector_type(8))) _Float16;
using f16x4 = __attribute__((ext_vector_type(4))) _Float16;

// ---------------------------------------------------------------------------
// Kernel 1 (wsplit): W2p[kc][e][d] = sum_{c in kc-chunk} Wm2[e][c]*Wmsg[c][d]
// Grid (16,16,4) = 1024 blocks, K-chunk 128.
// ---------------------------------------------------------------------------
__global__ __launch_bounds__(256) void wsplit_kernel(
    const float* __restrict__ Wm, const float* __restrict__ Wmsg,
    float* __restrict__ W2p) {
  __shared__ float As[32][33];
  __shared__ float Bs[32][33];
  const int t = threadIdx.x;
  const int db = blockIdx.x * 32;
  const int eb = blockIdx.y * 32;
  const int kc = blockIdx.z;
  const int tx = t % 16, ty = t / 16;
  const int lr = t / 8;
  const int lc = (t % 8) * 4;
  float a00 = 0.f, a01 = 0.f, a10 = 0.f, a11 = 0.f;
  for (int c0 = kc * 128; c0 < kc * 128 + 128; c0 += 32) {
    float4 av = *(const float4*)&Wm[(size_t)(eb + lr) * 1024 + 512 + c0 + lc];
    float4 bv = *(const float4*)&Wmsg[(size_t)(c0 + lr) * 512 + db + lc];
    As[lr][lc + 0] = av.x; As[lr][lc + 1] = av.y;
    As[lr][lc + 2] = av.z; As[lr][lc + 3] = av.w;
    Bs[lr][lc + 0] = bv.x; Bs[lr][lc + 1] = bv.y;
    Bs[lr][lc + 2] = bv.z; Bs[lr][lc + 3] = bv.w;
    __syncthreads();
#pragma unroll
    for (int kk = 0; kk < 32; kk++) {
      float x0 = As[2 * ty + 0][kk], x1 = As[2 * ty + 1][kk];
      float y0 = Bs[kk][2 * tx + 0], y1 = Bs[kk][2 * tx + 1];
      a00 += x0 * y0; a01 += x0 * y1;
      a10 += x1 * y0; a11 += x1 * y1;
    }
    __syncthreads();
  }
  float* base = W2p + (size_t)kc * 512 * 512;
  base[(size_t)(eb + 2 * ty + 0) * 512 + db + 2 * tx + 0] = a00;
  base[(size_t)(eb + 2 * ty + 0) * 512 + db + 2 * tx + 1] = a01;
  base[(size_t)(eb + 2 * ty + 1) * 512 + db + 2 * tx + 0] = a10;
  base[(size_t)(eb + 2 * ty + 1) * 512 + db + 2 * tx + 1] = a11;
}

// ---------------------------------------------------------------------------
// Kernel 2 (w2fin): fused finishers.
//  - blocks [0,1024):    W16[e][512+d] = fp16(sum_kc W2p[kc][e][d])
//  - blocks [1024,1280): W16[e][d]     = fp16(Wm[e][d]), d<512
//  - blocks [1280,1282): bias_eff[e]   = b_merge[e] + b_msg . Wm2[e]
// ---------------------------------------------------------------------------
__global__ __launch_bounds__(256) void w2fin_kernel(
    const float* __restrict__ W2p, const float* __restrict__ Wm,
    const float* __restrict__ b_msg, const float* __restrict__ b_merge,
    _Float16* __restrict__ W16, float* __restrict__ bias_eff) {
  const int bx = blockIdx.x;
  const int t = threadIdx.x;
  if (bx < 1024) {
    const int i = bx * 256 + t;  // 0..262143
    const int e = i >> 9;
    const int d = i & 511;
    float acc = 0.f;
#pragma unroll
    for (int kc = 0; kc < 4; ++kc)
      acc += W2p[(size_t)kc * 512 * 512 + (size_t)e * 512 + d];
    W16[(size_t)e * 1024 + 512 + d] = (_Float16)acc;
  } else if (bx < 1280) {
    const int i = (bx - 1024) * 256 + t;  // 0..65535 float4 ids
    const int e = i >> 7;
    const int c4 = (i & 127) * 4;
    float4 v = *(const float4*)&Wm[(size_t)e * 1024 + c4];
    f16x4 o = {(_Float16)v.x, (_Float16)v.y, (_Float16)v.z, (_Float16)v.w};
    *(f16x4*)&W16[(size_t)e * 1024 + c4] = o;
  } else {
    const int e = (bx - 1280) * 256 + t;  // 0..511
    const float4* bp = (const float4*)b_msg;
    const float4* wp = (const float4*)&Wm[(size_t)e * 1024 + 512];
    float acc = 0.f;
    for (int c = 0; c < 128; c++) {
      float4 b4 = bp[c], w4 = wp[c];
      acc += b4.x * w4.x + b4.y * w4.y + b4.z * w4.z + b4.w * w4.w;
    }
    bias_eff[e] = acc + b_merge[e];
  }
}

// ---------------------------------------------------------------------------
// Kernel 3 (gram2): fused fp32->fp16 hi/lo split + split-precision Gram.
//   C1p[s] = Hi_I . Hi_J^T ; C2p[s] = Hi_I . Lo_J^T   over K-chunk s (512).
// Reads h directly; reg-stage + cvt + ds_write (XOR-swizzled), double-
// buffered LDS (one barrier per K-step); next-tile loads issued before MFMA
// phase (T14). Diagonal blocks (I==J) load once and side-write A16 = fp16(h).
// Grid (2,2,GSLICES); LDS 96 KB -> 1 block/CU.
// ---------------------------------------------------------------------------
__global__ __launch_bounds__(256, 1) void gram2_kernel(
    const float* __restrict__ h, _Float16* __restrict__ A16,
    float* __restrict__ C1p, float* __restrict__ C2p) {
  const int t = threadIdx.x;
  const int lane = t & 63;
  const int w = t >> 6;
  const int I = blockIdx.x * 128;
  const int J = blockIdx.y * 128;
  const int s = blockIdx.z;
  const bool diag = (I == J);
  __shared__ char sHiI[2 * 16384];
  __shared__ char sHiJ[2 * 16384];
  __shared__ char sLoJ[2 * 16384];
  const int wm = w >> 1, wn = w & 1;
  const int rlane = lane & 15;
  const int kq = lane >> 4;

  f32x4 c1[4][4] = {};
  f32x4 c2[4][4] = {};

  const float* hI = h + (size_t)I * RBD + (size_t)s * 512;
  const float* hJ = h + (size_t)J * RBD + (size_t)s * 512;

  float4 rI[8], rJ[8];
  // prologue: load kt=0 tiles
#pragma unroll
  for (int u = 0; u < 8; ++u) {
    const int f = u * 256 + t;           // 0..2047
    const int row = f >> 4, c4 = f & 15;
    const size_t off = (size_t)row * RBD + c4 * 4;
    rI[u] = *(const float4*)&hI[off];
    if (!diag) rJ[u] = *(const float4*)&hJ[off];
  }

#pragma unroll
  for (int kt = 0; kt < 8; ++kt) {
    char* bHiI = sHiI + (kt & 1) * 16384;
    char* bHiJ = sHiJ + (kt & 1) * 16384;
    char* bLoJ = sLoJ + (kt & 1) * 16384;
    // ---- cvt + ds_write current tiles (+ A16 side-write on diagonal) ----
#pragma unroll
    for (int u = 0; u < 8; ++u) {
      const int f = u * 256 + t;
      const int row = f >> 4, c4 = f & 15;
      const int boff = row * 128 + (((c4 >> 1) ^ (row & 7)) << 4) + (c4 & 1) * 8;
      float4 vI = rI[u];
      f16x4 hiI = {(_Float16)vI.x, (_Float16)vI.y, (_Float16)vI.z,
                   (_Float16)vI.w};
      *(f16x4*)(bHiI + boff) = hiI;
      if (diag) {
        f16x4 loI = {(_Float16)(vI.x - (float)hiI[0]),
                     (_Float16)(vI.y - (float)hiI[1]),
                     (_Float16)(vI.z - (float)hiI[2]),
                     (_Float16)(vI.w - (float)hiI[3])};
        *(f16x4*)(bHiJ + boff) = hiI;
        *(f16x4*)(bLoJ + boff) = loI;
        *(f16x4*)&A16[(size_t)(I + row) * RBD + (size_t)s * 512 + kt * 64 +
                      c4 * 4] = hiI;
      } else {
        float4 vJ = rJ[u];
        f16x4 hiJ = {(_Float16)vJ.x, (_Float16)vJ.y, (_Float16)vJ.z,
                     (_Float16)vJ.w};
        f16x4 loJ = {(_Float16)(vJ.x - (float)hiJ[0]),
                     (_Float16)(vJ.y - (float)hiJ[1]),
                     (_Float16)(vJ.z - (float)hiJ[2]),
                     (_Float16)(vJ.w - (float)hiJ[3])};
        *(f16x4*)(bHiJ + boff) = hiJ;
        *(f16x4*)(bLoJ + boff) = loJ;
      }
    }
    __syncthreads();
    // ---- issue next-tile loads (in flight across the MFMA phase) ----
    if (kt < 7) {
#pragma unroll
      for (int u = 0; u < 8; ++u) {
        const int f = u * 256 + t;
        const int row = f >> 4, c4 = f & 15;
        const size_t off = (size_t)row * RBD + (kt + 1) * 64 + c4 * 4;
        rI[u] = *(const float4*)&hI[off];
        if (!diag) rJ[u] = *(const float4*)&hJ[off];
      }
    }
    // ---- MFMA phase on buf (kt&1) ----
#pragma unroll
    for (int ks = 0; ks < 2; ++ks) {
      f16x8 ai[4], bj[4], lj[4];
#pragma unroll
      for (int i = 0; i < 4; ++i) {
        const int row = wm * 64 + i * 16 + rlane;
        const int slot = (ks * 4 + kq) ^ (row & 7);
        ai[i] = *(const f16x8*)(bHiI + row * 128 + slot * 16);
      }
#pragma unroll
      for (int j = 0; j < 4; ++j) {
        const int row = wn * 64 + j * 16 + rlane;
        const int slot = (ks * 4 + kq) ^ (row & 7);
        bj[j] = *(const f16x8*)(bHiJ + row * 128 + slot * 16);
        lj[j] = *(const f16x8*)(bLoJ + row * 128 + slot * 16);
      }
#pragma unroll
      for (int i = 0; i < 4; ++i)
#pragma unroll
        for (int j = 0; j < 4; ++j) {
          c1[i][j] = __builtin_amdgcn_mfma_f32_16x16x32_f16(ai[i], bj[j],
                                                            c1[i][j], 0, 0, 0);
          c2[i][j] = __builtin_amdgcn_mfma_f32_16x16x32_f16(ai[i], lj[j],
                                                            c2[i][j], 0, 0, 0);
        }
    }
    // buffer parity separates next overwrite from these reads by 2 barriers
  }

#pragma unroll
  for (int i = 0; i < 4; ++i) {
#pragma unroll
    for (int reg = 0; reg < 4; ++reg) {
      const int gr = I + wm * 64 + i * 16 + kq * 4 + reg;
      const size_t base = ((size_t)s * 256 + gr) * 256 + J + wn * 64 + rlane;
      float* p1 = C1p + base;
      float* p2 = C2p + base;
#pragma unroll
      for (int j = 0; j < 4; ++j) {
        p1[j * 16] = c1[i][j][reg];
        p2[j * 16] = c2[i][j][reg];
      }
    }
  }
}

// ---------------------------------------------------------------------------
// Kernel 4: reduce partials in fixed order -> sims; stable top-4 (strict >,
// first index wins = jax.lax.top_k tie rule). 256 thr: 16 lanes per neighbor.
// G[r][j] = sum_s C1p[s][r][j] + C2p[s][r][j] + C2p[s][j][r]
// ---------------------------------------------------------------------------
__global__ __launch_bounds__(256) void reduce_topk_kernel(
    const float* __restrict__ C1p, const float* __restrict__ C2p,
    const int* __restrict__ nbrs, int* __restrict__ sel,
    float* __restrict__ fanin) {
  const int r = blockIdx.x;
  const int t = threadIdx.x;
  const int n = t >> 4;       // 0..15
  const int sq = t & 15;      // 0..15
  __shared__ float sims_s[N_];
  __shared__ int nb_s[N_];
  if (t < N_) nb_s[t] = nbrs[r * N_ + t];
  __syncthreads();
  const int j = nb_s[n];
  float acc = 0.f;
#pragma unroll
  for (int s = sq * 4; s < sq * 4 + 4; ++s) {
    const size_t rj = ((size_t)s * 256 + r) * 256 + j;
    const size_t jr = ((size_t)s * 256 + j) * 256 + r;
    acc += C1p[rj] + C2p[rj] + C2p[jr];
  }
  acc += __shfl_xor(acc, 1);
  acc += __shfl_xor(acc, 2);
  acc += __shfl_xor(acc, 4);
  acc += __shfl_xor(acc, 8);
  if (sq == 0) sims_s[n] = acc;
  __syncthreads();
  if (t == 0) {
    unsigned used = 0;
#pragma unroll
    for (int k = 0; k < K_; k++) {
      float best = -3.0e38f;
      int bi = 0;
      for (int nn = 0; nn < N_; nn++) {
        if (used & (1u << nn)) continue;
        float vv = sims_s[nn];
        if (vv > best) { best = vv; bi = nn; }
      }
      used |= 1u << bi;
      sel[r * K_ + k] = nb_s[bi];
    }
    if (r == 0) *fanin = 4.0f;
  }
}

// ---------------------------------------------------------------------------
// Kernel 5: Am16[r*64+b][d] = fp16(mean_k A16[sel[r][k]][b][d])  (fp32 mean)
// ---------------------------------------------------------------------------
__global__ __launch_bounds__(256) void am_kernel(
    const _Float16* __restrict__ A16, const int* __restrict__ sel,
    _Float16* __restrict__ Am16) {
  const int r = blockIdx.x;
  const int rs = blockIdx.y * 16;
  const int t = threadIdx.x;
  __shared__ int sel_s[K_];
  if (t < K_) sel_s[t] = sel[r * K_ + t];
  __syncthreads();
  const size_t s0 = (size_t)sel_s[0] * RBD;
  const size_t s1 = (size_t)sel_s[1] * RBD;
  const size_t s2 = (size_t)sel_s[2] * RBD;
  const size_t s3 = (size_t)sel_s[3] * RBD;
  for (int i = t; i < 1024; i += 256) {
    const int row = rs + (i >> 6);
    const int c = (i & 63) * 8;
    const size_t off = (size_t)row * 512 + c;
    f16x8 q0 = *(const f16x8*)&A16[s0 + off];
    f16x8 q1 = *(const f16x8*)&A16[s1 + off];
    f16x8 q2 = *(const f16x8*)&A16[s2 + off];
    f16x8 q3 = *(const f16x8*)&A16[s3 + off];
    f16x8 m;
#pragma unroll
    for (int e = 0; e < 8; ++e)
      m[e] = (_Float16)(0.25f * ((float)q0[e] + (float)q1[e] + (float)q2[e] +
                                 (float)q3[e]));
    *(f16x8*)&Am16[((size_t)r * 64 + row) * 512 + c] = m;
  }
}

// ---------------------------------------------------------------------------
// Kernel 6: fp16 MFMA GEMM. out[m][e] = bias[e] + sum_k A[m][k]*W16[e][k]
// A: k<512 from A16[m][k], k>=512 from Am16[m][k-512]. M=16384,N=512,K=1024.
// ---------------------------------------------------------------------------
__global__ __launch_bounds__(256) void mfma_gemm_kernel(
    const _Float16* __restrict__ A16, const _Float16* __restrict__ Am16,
    const _Float16* __restrict__ W16, const float* __restrict__ bias,
    float* __restrict__ out) {
  const int t = threadIdx.x;
  const int lane = t & 63;
  const int w = t >> 6;
  const int m0 = blockIdx.y * 128;
  const int eb = blockIdx.x * 128;
  __shared__ char smemA[128 * 128];
  __shared__ char smemW[128 * 128];
  const int wm = w >> 1, wn = w & 1;
  const int rlane = lane & 15;
  const int kq = lane >> 4;
  const int row_in_sweep = t >> 3;
  const int slot_st = t & 7;

  f32x4 acc[4][4] = {};

  const char* Ab = (const char*)A16;
  const char* Amb = (const char*)Am16;
  const char* Wb = (const char*)W16;

  for (int kt = 0; kt < 16; ++kt) {
#pragma unroll
    for (int q = 0; q < 4; ++q) {
      const int row = q * 32 + row_in_sweep;
      const int slot = slot_st ^ (row & 7);
      const char* ga =
          (kt < 8)
              ? Ab + ((size_t)(m0 + row) * 1024 + kt * 128 + slot * 16)
              : Amb + ((size_t)(m0 + row) * 1024 + (kt - 8) * 128 + slot * 16);
      const char* gw = Wb + ((size_t)(eb + row) * 2048 + kt * 128 + slot * 16);
      char* la = smemA + q * 4096 + w * 1024;
      char* lw = smemW + q * 4096 + w * 1024;
      __builtin_amdgcn_global_load_lds((const g_u32*)ga, (l_u32*)la, 16, 0, 0);
      __builtin_amdgcn_global_load_lds((const g_u32*)gw, (l_u32*)lw, 16, 0, 0);
    }
    __syncthreads();
#pragma unroll
    for (int ks = 0; ks < 2; ++ks) {
      f16x8 a[4], b[4];
#pragma unroll
      for (int i = 0; i < 4; ++i) {
        const int row = wm * 64 + i * 16 + rlane;
        const int slot = (ks * 4 + kq) ^ (row & 7);
        a[i] = *(const f16x8*)(smemA + row * 128 + slot * 16);
      }
#pragma unroll
      for (int j = 0; j < 4; ++j) {
        const int row = wn * 64 + j * 16 + rlane;
        const int slot = (ks * 4 + kq) ^ (row & 7);
        b[j] = *(const f16x8*)(smemW + row * 128 + slot * 16);
      }
#pragma unroll
      for (int i = 0; i < 4; ++i)
#pragma unroll
        for (int j = 0; j < 4; ++j)
          acc[i][j] = __builtin_amdgcn_mfma_f32_16x16x32_f16(a[i], b[j],
                                                             acc[i][j], 0, 0, 0);
    }
    __syncthreads();
  }

  float bj[4];
#pragma unroll
  for (int j = 0; j < 4; ++j) bj[j] = bias[eb + wn * 64 + j * 16 + rlane];
#pragma unroll
  for (int i = 0; i < 4; ++i) {
#pragma unroll
    for (int reg = 0; reg < 4; ++reg) {
      const size_t m = (size_t)m0 + wm * 64 + i * 16 + kq * 4 + reg;
      float* po = out + m * 512 + eb + wn * 64 + rlane;
#pragma unroll
      for (int j = 0; j < 4; ++j) po[j * 16] = acc[i][j][reg] + bj[j];
    }
  }
}

// ---------------------------------------------------------------------------
// Fallback fp32 path (small workspace): round-1 kernels.
// ---------------------------------------------------------------------------
__global__ __launch_bounds__(256) void bias_kernel(
    const float* __restrict__ Wm, const float* __restrict__ b_msg,
    const float* __restrict__ b_merge, float* __restrict__ bias_eff) {
  const int e = blockIdx.x * 256 + threadIdx.x;
  const float4* bp = (const float4*)b_msg;
  const float4* wp = (const float4*)&Wm[(size_t)e * 1024 + 512];
  float acc = 0.f;
  for (int c = 0; c < 128; c++) {
    float4 b4 = bp[c], w4 = wp[c];
    acc += b4.x * w4.x + b4.y * w4.y + b4.z * w4.z + b4.w * w4.w;
  }
  bias_eff[e] = acc + b_merge[e];
}

__global__ __launch_bounds__(256) void sims_topk_kernel(
    const float* __restrict__ h, const int* __restrict__ nbrs,
    int* __restrict__ sel, float* __restrict__ fanin) {
  const int r = blockIdx.x;
  const int t = threadIdx.x;
  const int lane = t & 63;
  const int wave = t >> 6;
  __shared__ float sims_s[N_];
  __shared__ int nb_s[N_];
  if (t < N_) nb_s[t] = nbrs[r * N_ + t];
  __syncthreads();
  const int n0 = wave * 4;
  const float4* hr  = (const float4*)(h + (size_t)r * RBD);
  const float4* hn0 = (const float4*)(h + (size_t)nb_s[n0 + 0] * RBD);
  const float4* hn1 = (const float4*)(h + (size_t)nb_s[n0 + 1] * RBD);
  const float4* hn2 = (const float4*)(h + (size_t)nb_s[n0 + 2] * RBD);
  const float4* hn3 = (const float4*)(h + (size_t)nb_s[n0 + 3] * RBD);
  float a0 = 0.f, a1 = 0.f, a2 = 0.f, a3 = 0.f;
  for (int i = lane; i < RBD / 4; i += 64) {
    float4 x = hr[i];
    float4 y0 = hn0[i], y1 = hn1[i], y2 = hn2[i], y3 = hn3[i];
    a0 += x.x * y0.x + x.y * y0.y + x.z * y0.z + x.w * y0.w;
    a1 += x.x * y1.x + x.y * y1.y + x.z * y1.z + x.w * y1.w;
    a2 += x.x * y2.x + x.y * y2.y + x.z * y2.z + x.w * y2.w;
    a3 += x.x * y3.x + x.y * y3.y + x.z * y3.z + x.w * y3.w;
  }
  float v[4] = {a0, a1, a2, a3};
#pragma unroll
  for (int n = 0; n < 4; n++) {
    float x = v[n];
#pragma unroll
    for (int off = 32; off > 0; off >>= 1) x += __shfl_down(x, off);
    if (lane == 0) sims_s[n0 + n] = x;
  }
  __syncthreads();
  if (t == 0) {
    unsigned used = 0;
#pragma unroll
    for (int k = 0; k < K_; k++) {
      float best = -3.0e38f;
      int bi = 0;
      for (int n = 0; n < N_; n++) {
        if (used & (1u << n)) continue;
        float vv = sims_s[n];
        if (vv > best) { best = vv; bi = n; }
      }
      used |= 1u << bi;
      sel[r * K_ + k] = nb_s[bi];
    }
    if (r == 0) *fanin = 4.0f;
  }
}

__global__ __launch_bounds__(256) void w2eff_f32_kernel(
    const float* __restrict__ Wm, const float* __restrict__ Wmsg,
    float* __restrict__ W2) {
  __shared__ float As[32][33];
  __shared__ float Bs[32][33];
  const int t = threadIdx.x;
  const int eb = blockIdx.y * 32;
  const int db = blockIdx.x * 32;
  const int tx = t % 16, ty = t / 16;
  const int lr = t / 8;
  const int lc = (t % 8) * 4;
  float a00 = 0.f, a01 = 0.f, a10 = 0.f, a11 = 0.f;
  for (int c0 = 0; c0 < 512; c0 += 32) {
    float4 av = *(const float4*)&Wm[(size_t)(eb + lr) * 1024 + 512 + c0 + lc];
    float4 bv = *(const float4*)&Wmsg[(size_t)(c0 + lr) * 512 + db + lc];
    As[lr][lc + 0] = av.x; As[lr][lc + 1] = av.y;
    As[lr][lc + 2] = av.z; As[lr][lc + 3] = av.w;
    Bs[lr][lc + 0] = bv.x; Bs[lr][lc + 1] = bv.y;
    Bs[lr][lc + 2] = bv.z; Bs[lr][lc + 3] = bv.w;
    __syncthreads();
#pragma unroll
    for (int kk = 0; kk < 32; kk++) {
      float x0 = As[2 * ty + 0][kk], x1 = As[2 * ty + 1][kk];
      float y0 = Bs[kk][2 * tx + 0], y1 = Bs[kk][2 * tx + 1];
      a00 += x0 * y0; a01 += x0 * y1;
      a10 += x1 * y0; a11 += x1 * y1;
    }
    __syncthreads();
  }
  W2[(size_t)(eb + 2 * ty + 0) * 512 + db + 2 * tx + 0] = a00;
  W2[(size_t)(eb + 2 * ty + 0) * 512 + db + 2 * tx + 1] = a01;
  W2[(size_t)(eb + 2 * ty + 1) * 512 + db + 2 * tx + 0] = a10;
  W2[(size_t)(eb + 2 * ty + 1) * 512 + db + 2 * tx + 1] = a11;
}

__global__ __launch_bounds__(256) void fused_gemm_f32_kernel(
    const float* __restrict__ h, const int* __restrict__ sel,
    const float* __restrict__ Wm, const float* __restrict__ W2,
    const float* __restrict__ bias_eff, float* __restrict__ out) {
  const int r = blockIdx.y;
  const int eb = blockIdx.x * 256;
  const int t = threadIdx.x;
  __shared__ float As[64][33];
  __shared__ float Ws[256][33];
  __shared__ int sel_s[K_];
  if (t < K_) sel_s[t] = sel[r * K_ + t];
  __syncthreads();
  const size_t hr = (size_t)r * RBD;
  const size_t s0 = (size_t)sel_s[0] * RBD;
  const size_t s1 = (size_t)sel_s[1] * RBD;
  const size_t s2 = (size_t)sel_s[2] * RBD;
  const size_t s3 = (size_t)sel_s[3] * RBD;
  const int tb = t % 8;
  const int te = t / 8;
  const int ab = t / 4;
  const int ac = (t % 4) * 8;
  float acc[8][8] = {};
  for (int d0 = 0; d0 < 1024; d0 += 32) {
    if (d0 < 512) {
      const float* src = h + hr + (size_t)ab * 512 + d0 + ac;
      float4 v0 = *(const float4*)(src);
      float4 v1 = *(const float4*)(src + 4);
      As[ab][ac + 0] = v0.x; As[ab][ac + 1] = v0.y;
      As[ab][ac + 2] = v0.z; As[ab][ac + 3] = v0.w;
      As[ab][ac + 4] = v1.x; As[ab][ac + 5] = v1.y;
      As[ab][ac + 6] = v1.z; As[ab][ac + 7] = v1.w;
    } else {
      const size_t off = (size_t)ab * 512 + (d0 - 512) + ac;
      const float* p0 = h + s0 + off;
      const float* p1 = h + s1 + off;
      const float* p2 = h + s2 + off;
      const float* p3 = h + s3 + off;
      float4 q0 = *(const float4*)p0, q0b = *(const float4*)(p0 + 4);
      float4 q1 = *(const float4*)p1, q1b = *(const float4*)(p1 + 4);
      float4 q2 = *(const float4*)p2, q2b = *(const float4*)(p2 + 4);
      float4 q3 = *(const float4*)p3, q3b = *(const float4*)(p3 + 4);
      As[ab][ac + 0] = 0.25f * (q0.x + q1.x + q2.x + q3.x);
      As[ab][ac + 1] = 0.25f * (q0.y + q1.y + q2.y + q3.y);
      As[ab][ac + 2] = 0.25f * (q0.z + q1.z + q2.z + q3.z);
      As[ab][ac + 3] = 0.25f * (q0.w + q1.w + q2.w + q3.w);
      As[ab][ac + 4] = 0.25f * (q0b.x + q1b.x + q2b.x + q3b.x);
      As[ab][ac + 5] = 0.25f * (q0b.y + q1b.y + q2b.y + q3b.y);
      As[ab][ac + 6] = 0.25f * (q0b.z + q1b.z + q2b.z + q3b.z);
      As[ab][ac + 7] = 0.25f * (q0b.w + q1b.w + q2b.w + q3b.w);
    }
    {
      const float* src = (d0 < 512)
          ? (Wm + (size_t)(eb + t) * 1024 + d0)
          : (W2 + (size_t)(eb + t) * 512 + (d0 - 512));
#pragma unroll
      for (int j = 0; j < 8; j++) {
        float4 v = *(const float4*)(src + 4 * j);
        Ws[t][4 * j + 0] = v.x; Ws[t][4 * j + 1] = v.y;
        Ws[t][4 * j + 2] = v.z; Ws[t][4 * j + 3] = v.w;
      }
    }
    __syncthreads();
#pragma unroll
    for (int kk = 0; kk < 32; kk++) {
      float a[8], wv[8];
#pragma unroll
      for (int i = 0; i < 8; i++) a[i] = As[tb + 8 * i][kk];
#pragma unroll
      for (int j = 0; j < 8; j++) wv[j] = Ws[te + 32 * j][kk];
#pragma unroll
      for (int i = 0; i < 8; i++)
#pragma unroll
        for (int j = 0; j < 8; j++) acc[i][j] += a[i] * wv[j];
    }
    __syncthreads();
  }
  float be[8];
#pragma unroll
  for (int j = 0; j < 8; j++) be[j] = bias_eff[eb + te + 32 * j];
#pragma unroll
  for (int i = 0; i < 8; i++) {
    const int b = tb + 8 * i;
#pragma unroll
    for (int j = 0; j < 8; j++) {
      const int e = eb + te + 32 * j;
      out[hr + (size_t)b * 512 + e] = acc[i][j] + be[j];
    }
  }
}

// ---------------------------------------------------------------------------
extern "C" void kernel_launch(void* const* d_in, const int* in_sizes, int n_in,
                              void* d_out, int out_size, void* d_ws,
                              size_t ws_size, hipStream_t stream) {
  const float* h       = (const float*)d_in[0];
  const int*   nbrs    = (const int*)d_in[1];
  const float* W_msg   = (const float*)d_in[2];
  const float* b_msg   = (const float*)d_in[3];
  const float* W_merge = (const float*)d_in[4];
  const float* b_merge = (const float*)d_in[5];
  float* out = (float*)d_out;
  char* ws = (char*)d_ws;

  const size_t SZ_PART = (size_t)GSLICES * 256 * 256 * 4;  // 16.78 MB each
  const size_t SZ_A = (size_t)M_TOT * 512 * 2;             // 16.78 MB each
  const size_t SZ_W = (size_t)512 * 1024 * 2;              // 1 MB
  size_t off = 0;
  int*      sel      = (int*)(ws + off);      off += 4096;
  float*    bias_eff = (float*)(ws + off);    off += 4096;
  float*    C1p      = (float*)(ws + off);    off += SZ_PART;
  float*    C2p      = (float*)(ws + off);    off += SZ_PART;
  _Float16* A16      = (_Float16*)(ws + off); off += SZ_A;
  _Float16* Am16     = (_Float16*)(ws + off); off += SZ_A;
  _Float16* W16      = (_Float16*)(ws + off); off += SZ_W;
  const size_t NEED = off;
  // W2p (4 MB) aliases C1p: consumed by w2fin before gram2 writes C1p.
  float* W2p = C1p;

  if (ws_size >= NEED) {
    wsplit_kernel<<<dim3(16, 16, 4), 256, 0, stream>>>(W_merge, W_msg, W2p);
    w2fin_kernel<<<1282, 256, 0, stream>>>(W2p, W_merge, b_msg, b_merge, W16,
                                           bias_eff);
    gram2_kernel<<<dim3(2, 2, GSLICES), 256, 0, stream>>>(h, A16, C1p, C2p);
    reduce_topk_kernel<<<R_, 256, 0, stream>>>(C1p, C2p, nbrs, sel,
                                               out + OUT_ELEMS);
    am_kernel<<<dim3(R_, 4), 256, 0, stream>>>(A16, sel, Am16);
    mfma_gemm_kernel<<<dim3(4, 128), 256, 0, stream>>>(A16, Am16, W16,
                                                       bias_eff, out);
  } else {
    int*   fsel     = (int*)ws;
    float* W2       = (float*)(ws + 4096);
    float* fbias    = (float*)(ws + 4096 + 512 * 512 * 4);
    sims_topk_kernel<<<R_, 256, 0, stream>>>(h, nbrs, fsel, out + OUT_ELEMS);
    bias_kernel<<<2, 256, 0, stream>>>(W_merge, b_msg, b_merge, fbias);
    w2eff_f32_kernel<<<dim3(16, 16), 256, 0, stream>>>(W_merge, W_msg, W2);
    fused_gemm_f32_kernel<<<dim3(2, R_), 256, 0, stream>>>(h, fsel, W_merge,
                                                           W2, fbias, out);
  }
}